// Round 1
// baseline (124.960 us; speedup 1.0000x reference)
//
#include <hip/hip_runtime.h>
#include <math.h>

// Problem constants (fixed by reference: inp (4,16,32,32) f32, weight (64,144) f32)
constexpr int F_IN   = 144;   // 16 ch * 9 taps
constexpr int F_OUT  = 64;
constexpr int H_IMG  = 32;
constexpr int W_IMG  = 32;
constexpr int NPIX   = 4 * H_IMG * W_IMG;  // 4096
#define MAX_SPIKE 100.0f

// ---------------------------------------------------------------------------
// Kernel 1: weight quantization (single block).
//   w (64,144) -> wq (144,64)  [transposed for coalesced reads in kernel 2]
//   wq = round(clip(tanh(w)/alpha, -1, 1)*127) * alpha / 127,  alpha = max|tanh(w)|
// tanh computed in double then cast: correctly-rounded f32 tanh.
// round = rintf (half-to-even, matches jnp.round / np.round).
// ---------------------------------------------------------------------------
__global__ __launch_bounds__(1024) void quant_weights_kernel(
    const float* __restrict__ w,
    float* __restrict__ wq)
{
    __shared__ float tsh[F_OUT * F_IN];   // 36 KB tanh cache
    __shared__ float red[1024];
    const int tid = threadIdx.x;

    float m = 0.f;
    for (int i = tid; i < F_OUT * F_IN; i += 1024) {
        float t = (float)::tanh((double)w[i]);   // i = o*144 + f layout
        tsh[i] = t;
        m = fmaxf(m, fabsf(t));
    }
    red[tid] = m;
    __syncthreads();
    for (int s = 512; s > 0; s >>= 1) {
        if (tid < s) red[tid] = fmaxf(red[tid], red[tid + s]);
        __syncthreads();
    }
    const float alpha = red[0];

    for (int i = tid; i < F_OUT * F_IN; i += 1024) {
        const int f = i >> 6;     // 0..143
        const int o = i & 63;     // 0..63
        float t = tsh[o * F_IN + f];
        float x = t / alpha;                          // f32 divide (mirrors np)
        x = fminf(fmaxf(x, -1.f), 1.f) * 127.f;       // clip then *qmax
        float r = rintf(x);                           // round half-to-even
        wq[i] = r * alpha / 127.f;                    // mul then div (mirrors np)
    }
}

// ---------------------------------------------------------------------------
// Kernel 2: one block per pixel (64 threads = 1 wave), one thread per out-ch.
//   1) stage 144 patch values (zero-pad border, then <0.1 -> 100) into LDS
//   2) stable sort via rank counting (ties broken by original index ==
//      jnp.argsort(stable) semantics)
//   3) per-thread sequential scan over sorted order: cumsum(w), cumsum(s*w),
//      q = iws / clip(ws-1, 1e-10, 1e10), three masks in reference order,
//      min over k.
// fp contract OFF so cumsums round exactly like numpy (mul, then add).
// ---------------------------------------------------------------------------
__global__ __launch_bounds__(64) void spike_conv_kernel(
    const float* __restrict__ inp,   // (4,16,32,32)
    const float* __restrict__ wq,    // (144,64)
    float* __restrict__ out)         // (4,64,32,32)
{
#pragma clang fp contract(off)
    __shared__ float vals[F_IN];
    __shared__ float sv[F_IN];
    __shared__ int   sidx[F_IN];

    const int p   = blockIdx.x;          // pixel id
    const int b   = p >> 10;
    const int l   = p & 1023;
    const int h   = l >> 5;
    const int w   = l & 31;
    const int tid = threadIdx.x;

    // stage patch (feature f = c*9 + kh*3 + kw)
    for (int i = tid; i < F_IN; i += 64) {
        const int c  = i / 9;
        const int r  = i - c * 9;
        const int kh = r / 3;
        const int kw = r - kh * 3;
        const int hh = h + kh - 1;
        const int ww = w + kw - 1;
        float v = 0.f;
        if (hh >= 0 && hh < H_IMG && ww >= 0 && ww < W_IMG)
            v = inp[((b * 16 + c) * H_IMG + hh) * W_IMG + ww];
        v = (v < 0.1f) ? MAX_SPIKE : v;
        vals[i] = v;
    }
    __syncthreads();

    // stable rank sort: rank(i) = #{j : v[j] < v[i]  or  (v[j]==v[i] and j<i)}
    for (int i = tid; i < F_IN; i += 64) {
        const float vi = vals[i];
        int rank = 0;
        for (int j = 0; j < F_IN; ++j) {
            const float vj = vals[j];
            rank += (vj < vi) || (vj == vi && j < i);
        }
        sv[rank]   = vi;
        sidx[rank] = i;
    }
    __syncthreads();

    // per-output-channel sequential scan
    const int o = tid;
    float ws  = 0.f;
    float iws = 0.f;
    float mn  = 3.4e38f;
    for (int k = 0; k < F_IN; ++k) {
        const float s  = sv[k];          // LDS broadcast
        const int   f  = sidx[k];        // LDS broadcast
        const float wv = wq[f * F_OUT + o];  // coalesced, L1/L2-hot
        ws += wv;
        const float prod = s * wv;       // separate rounding (no FMA)
        iws += prod;
        float d = ws - 1.0f;
        d = fminf(fmaxf(d, 1e-10f), 1e10f);
        const float q = iws / d;         // IEEE f32 divide
        float spike = (ws < 1.0f) ? MAX_SPIKE : q;
        spike = (spike < s) ? MAX_SPIKE : spike;
        const float nxt = (k < F_IN - 1) ? sv[k + 1] : 1.0f;
        spike = (spike > nxt) ? MAX_SPIKE : spike;
        mn = fminf(mn, spike);
    }
    out[(b * F_OUT + o) * 1024 + l] = mn;
}

extern "C" void kernel_launch(void* const* d_in, const int* in_sizes, int n_in,
                              void* d_out, int out_size, void* d_ws, size_t ws_size,
                              hipStream_t stream) {
    const float* inp = (const float*)d_in[0];   // 65536 elems
    const float* w   = (const float*)d_in[1];   // 9216 elems
    float* out = (float*)d_out;                 // 262144 elems
    float* wq  = (float*)d_ws;                  // 9216 floats scratch

    quant_weights_kernel<<<1, 1024, 0, stream>>>(w, wq);
    spike_conv_kernel<<<NPIX, 64, 0, stream>>>(inp, wq, out);
}

// Round 2
// 103.053 us; speedup vs baseline: 1.2126x; 1.2126x over previous
//
#include <hip/hip_runtime.h>
#include <math.h>

// Problem constants (fixed by reference: inp (4,16,32,32) f32, weight (64,144) f32)
constexpr int F_IN   = 144;   // 16 ch * 9 taps
constexpr int F_OUT  = 64;
constexpr int H_IMG  = 32;
constexpr int W_IMG  = 32;
constexpr int NPIX   = 4 * H_IMG * W_IMG;  // 4096
#define MAX_SPIKE 100.0f

// ---------------------------------------------------------------------------
// Weight quantization, parallelized (was 60us single-block; now 3 tiny steps):
//   memsetAsync(alpha=0) -> absmax kernel (atomicMax on uint bits) -> apply.
// tanh computed in double then cast -> correctly-rounded f32 tanh (matches np
// within round-1-validated tolerance). rintf = half-to-even like np.round.
// ---------------------------------------------------------------------------
__global__ __launch_bounds__(256) void quant_absmax_kernel(
    const float* __restrict__ w, unsigned* __restrict__ alpha_bits)
{
    const int i = blockIdx.x * 256 + threadIdx.x;   // grid covers 9216 exactly
    const float t = (float)::tanh((double)w[i]);
    unsigned u = __float_as_uint(fabsf(t));         // positive floats: uint order == float order
    for (int s = 32; s > 0; s >>= 1) {
        unsigned o = (unsigned)__shfl_xor((int)u, s, 64);
        u = (o > u) ? o : u;
    }
    if ((threadIdx.x & 63) == 0) atomicMax(alpha_bits, u);
}

__global__ __launch_bounds__(256) void quant_apply_kernel(
    const float* __restrict__ w, const unsigned* __restrict__ alpha_bits,
    float* __restrict__ wqT)   // (144, 64) transposed for coalesced scan reads
{
#pragma clang fp contract(off)
    const int i = blockIdx.x * 256 + threadIdx.x;
    const float alpha = __uint_as_float(*alpha_bits);
    const int o = i / F_IN;
    const int f = i - o * F_IN;
    const float t = (float)::tanh((double)w[i]);
    float x = t / alpha;                       // f32 divide (mirrors np)
    x = fminf(fmaxf(x, -1.f), 1.f) * 127.f;    // clip then *qmax
    const float r = rintf(x);                  // round half-to-even
    wqT[f * F_OUT + o] = r * alpha / 127.f;    // mul then div (mirrors np)
}

// ---------------------------------------------------------------------------
// Spike conv: 4 pixels per 256-thread block, one wave per pixel, one lane per
// output channel.
//   1) stage 144 patch values; build u64 sort keys (bits<<8)|idx  -- exact
//      stable-argsort order (values all >= 0 so bit order == float order)
//   2) rank sort: rank_i = #{ key_j < key_i }  (1 cmp_u64 + addc per j)
//   3) build per-slot record: hi = bits(sv[k+1]) (sentinel sv[144]=1.0f),
//      lo = feature_idx*256 = byte offset of wq row  -> ONE ds_read_b64/iter
//   4) scan k: cumsum(w), cumsum(s*w), q = iws / max(ws-1, 1e-10) [IEEE div,
//      upper clamp provably never binds], three masks in reference order,
//      min. Early break at s==100 (later slots contribute exactly 100; mn
//      init = 100). Skip div+masks while the whole wave has ws<1 (all-masked).
// fp contract OFF so cumsums round exactly like numpy (mul, then add).
// ---------------------------------------------------------------------------
__global__ __launch_bounds__(256) void spike_conv_kernel(
    const float* __restrict__ inp,   // (4,16,32,32)
    const float* __restrict__ wq,    // (144,64)
    float* __restrict__ out)         // (4,64,32,32)
{
#pragma clang fp contract(off)
    __shared__ unsigned long long kr[4][F_IN];   // keys, then {nxt,off} records
    __shared__ float sv[4][F_IN + 1];            // sorted values + sentinel

    const int tid  = threadIdx.x;
    const int lane = tid & 63;
    const int wv_i = tid >> 6;                   // wave id = pixel-in-block
    const int p    = blockIdx.x * 4 + wv_i;      // pixel id
    const int b    = p >> 10;
    const int l    = p & 1023;
    const int h    = l >> 5;
    const int w    = l & 31;

    // ---- stage patch, build keys (feature f = c*9 + kh*3 + kw) ----
    float v0f = 0.f, v1f = 0.f, v2f = 0.f;
    unsigned long long key0, key1, key2;
    {
        int idx[3] = { lane, lane + 64, lane + 128 };
        float vals[3];
        for (int m = 0; m < 3; ++m) {
            const int i = idx[m];
            float v = MAX_SPIKE;
            if (i < F_IN) {
                const int c  = i / 9;
                const int r  = i - c * 9;
                const int kh = r / 3;
                const int kw = r - kh * 3;
                const int hh = h + kh - 1;
                const int ww = w + kw - 1;
                float x = 0.f;
                if (hh >= 0 && hh < H_IMG && ww >= 0 && ww < W_IMG)
                    x = inp[((b * 16 + c) * H_IMG + hh) * W_IMG + ww];
                v = (x < 0.1f) ? MAX_SPIKE : x;
                kr[wv_i][i] = ((unsigned long long)__float_as_uint(v) << 8)
                              | (unsigned)i;
            }
            vals[m] = v;
        }
        v0f = vals[0]; v1f = vals[1]; v2f = vals[2];
        key0 = ((unsigned long long)__float_as_uint(v0f) << 8) | (unsigned)idx[0];
        key1 = ((unsigned long long)__float_as_uint(v1f) << 8) | (unsigned)idx[1];
        key2 = ((unsigned long long)__float_as_uint(v2f) << 8) | (unsigned)idx[2];
        if (lane == 0) sv[wv_i][F_IN] = 1.0f;    // causality sentinel
    }
    __syncthreads();

    // ---- rank sort: keys unique -> strict < gives exact stable permutation
    int r0 = 0, r1 = 0, r2 = 0;
    {
        const unsigned long long* ks = kr[wv_i];
#pragma unroll 4
        for (int j = 0; j < F_IN; ++j) {
            const unsigned long long kj = ks[j];
            r0 += (kj < key0);
            r1 += (kj < key1);
            r2 += (kj < key2);
        }
    }
    __syncthreads();   // all key reads complete before we clobber kr below

    // ---- scatter sorted values + record-lo (wq row byte offset) ----
    {
        unsigned* krlo = (unsigned*)&kr[wv_i][0];   // little-endian: lo at +0
        sv[wv_i][r0] = v0f;  krlo[2 * r0] = (unsigned)lane << 8;
        sv[wv_i][r1] = v1f;  krlo[2 * r1] = (unsigned)(lane + 64) << 8;
        if (lane < F_IN - 128) {
            sv[wv_i][r2] = v2f;  krlo[2 * r2] = (unsigned)(lane + 128) << 8;
        }
    }
    __syncthreads();

    // ---- record-hi = bits of next sorted value ----
    {
        unsigned* krhi = (unsigned*)&kr[wv_i][0];
        for (int k = lane; k < F_IN; k += 64)
            krhi[2 * k + 1] = __float_as_uint(sv[wv_i][k + 1]);
    }
    __syncthreads();

    // ---- per-channel sequential scan ----
    const char* wqp = (const char*)(wq + lane);
    float s   = sv[wv_i][0];
    float ws  = 0.f;
    float iws = 0.f;
    float mn  = MAX_SPIKE;      // all-masked slots contribute exactly 100
    for (int k = 0; k < F_IN; ++k) {
        if (s >= MAX_SPIKE) break;            // sorted: rest contribute 100
        const unsigned long long rec = kr[wv_i][k];
        const float nxt = __uint_as_float((unsigned)(rec >> 32));
        const unsigned off = (unsigned)rec;   // f*256 bytes
        const float wvv = *(const float*)(wqp + off);   // coalesced, L1-hot
        ws += wvv;
        const float prod = s * wvv;           // separate rounding (no FMA)
        iws += prod;
        if (!__all(ws < 1.0f)) {              // whole-wave masked -> skip
            float d = ws - 1.0f;
            d = fmaxf(d, 1e-10f);             // upper clamp never binds (ws<=144)
            const float q = iws / d;          // IEEE f32 divide
            float spike = (ws < 1.0f) ? MAX_SPIKE : q;
            spike = (spike < s) ? MAX_SPIKE : spike;
            spike = (spike > nxt) ? MAX_SPIKE : spike;
            mn = fminf(mn, spike);
        }
        s = nxt;
    }
    out[(b * F_OUT + lane) * 1024 + l] = mn;
}

extern "C" void kernel_launch(void* const* d_in, const int* in_sizes, int n_in,
                              void* d_out, int out_size, void* d_ws, size_t ws_size,
                              hipStream_t stream) {
    const float* inp = (const float*)d_in[0];   // 65536 elems
    const float* w   = (const float*)d_in[1];   // 9216 elems
    float* out = (float*)d_out;                 // 262144 elems

    unsigned* alpha_bits = (unsigned*)d_ws;             // 4 B
    float*    wqT = (float*)((char*)d_ws + 256);        // 9216 floats

    hipMemsetAsync(alpha_bits, 0, sizeof(unsigned), stream);
    quant_absmax_kernel<<<36, 256, 0, stream>>>(w, alpha_bits);
    quant_apply_kernel<<<36, 256, 0, stream>>>(w, alpha_bits, wqT);
    spike_conv_kernel<<<NPIX / 4, 256, 0, stream>>>(inp, wqT, out);
}

// Round 3
// 100.076 us; speedup vs baseline: 1.2487x; 1.0297x over previous
//
#include <hip/hip_runtime.h>
#include <math.h>

// Problem constants (fixed by reference: inp (4,16,32,32) f32, weight (64,144) f32)
constexpr int F_IN   = 144;   // 16 ch * 9 taps
constexpr int F_OUT  = 64;
constexpr int H_IMG  = 32;
constexpr int W_IMG  = 32;
constexpr int NPIX   = 4 * H_IMG * W_IMG;  // 4096
#define MAX_SPIKE 100.0f

// ---------------------------------------------------------------------------
// Weight quantization, single kernel (was absmax+apply+memset = 3 dispatches):
// every block redundantly max-reduces raw |w| (9216 f32, L2-broadcast, cheap),
// then alpha = tanh(max w). Since our tanh (double->float cast) is correctly
// rounded hence monotone, and all w >= 0, tanh(max w) == max tanh(w) EXACTLY
// -> bit-identical to the round-2 (validated) two-kernel version.
// rintf = half-to-even like np.round. mul-then-div mirrors np rounding.
// ---------------------------------------------------------------------------
__global__ __launch_bounds__(256) void quant_fused_kernel(
    const float* __restrict__ w,
    float* __restrict__ wqT)   // (144,64) transposed for coalesced scan reads
{
#pragma clang fp contract(off)
    __shared__ float wred[4];
    const int tid = threadIdx.x;

    float m = 0.f;
    for (int i = tid; i < F_OUT * F_IN; i += 256)
        m = fmaxf(m, fabsf(w[i]));
    for (int s = 32; s > 0; s >>= 1)
        m = fmaxf(m, __shfl_xor(m, s, 64));
    if ((tid & 63) == 0) wred[tid >> 6] = m;
    __syncthreads();
    const float mw = fmaxf(fmaxf(wred[0], wred[1]), fmaxf(wred[2], wred[3]));
    const float alpha = (float)::tanh((double)mw);

    const int i = blockIdx.x * 256 + tid;   // 36*256 = 9216 exactly
    const int o = i / F_IN;
    const int f = i - o * F_IN;
    const float t = (float)::tanh((double)w[i]);
    float x = t / alpha;                       // f32 divide (mirrors np)
    x = fminf(fmaxf(x, -1.f), 1.f) * 127.f;    // clip then *qmax
    const float r = rintf(x);                  // round half-to-even
    wqT[f * F_OUT + o] = r * alpha / 127.f;    // mul then div (mirrors np)
}

// ---------------------------------------------------------------------------
// Spike conv: 4 pixels per 256-thread block, one wave per pixel, one lane per
// output channel.
//   1) stage 144 patch values; u64 sort keys (bits<<8)|idx == exact stable
//      argsort (values >= 0 so bit order == float order)
//   2) rank sort (keys unique -> strict < gives the exact permutation)
//   3) per-slot record in LDS: hi = bits(next sorted value), lo = wq row byte
//      offset -> ONE ds_read_b64 per scan iter
//   4) scan: cumsum(w), cumsum(s*w), q = iws / max(ws-1,1e-10) [IEEE div],
//      masks in reference order. KEY FACT: valid windows [s_k, sv[k+1]] are
//      non-overlapping and increasing, so the FIRST valid spike is the min
//      -> per-lane done flag, wave exits at __all(done). Early break at
//      s==100 (later slots contribute exactly 100; mn init = 100). Skip
//      div+masks while __all(ws<1) (those slots contribute exactly 100).
// All emitted values bit-identical to the validated round-2 kernel.
// fp contract OFF so cumsums round exactly like numpy (mul, then add).
// ---------------------------------------------------------------------------
__global__ __launch_bounds__(256) void spike_conv_kernel(
    const float* __restrict__ inp,   // (4,16,32,32)
    const float* __restrict__ wq,    // (144,64)
    float* __restrict__ out)         // (4,64,32,32)
{
#pragma clang fp contract(off)
    __shared__ unsigned long long kr[4][F_IN];   // keys, then {nxt,off} records
    __shared__ float sv[4][F_IN + 1];            // sorted values + sentinel

    const int tid  = threadIdx.x;
    const int lane = tid & 63;
    const int wv_i = tid >> 6;                   // wave id = pixel-in-block
    const int p    = blockIdx.x * 4 + wv_i;      // pixel id
    const int b    = p >> 10;
    const int l    = p & 1023;
    const int h    = l >> 5;
    const int w    = l & 31;

    // ---- stage patch, build keys (feature f = c*9 + kh*3 + kw) ----
    float v0f, v1f, v2f;
    unsigned long long key0, key1, key2;
    {
        int idx[3] = { lane, lane + 64, lane + 128 };
        float vals[3];
        for (int m = 0; m < 3; ++m) {
            const int i = idx[m];
            float v = MAX_SPIKE;
            if (i < F_IN) {
                const int c  = i / 9;
                const int r  = i - c * 9;
                const int kh = r / 3;
                const int kw = r - kh * 3;
                const int hh = h + kh - 1;
                const int ww = w + kw - 1;
                float x = 0.f;
                if (hh >= 0 && hh < H_IMG && ww >= 0 && ww < W_IMG)
                    x = inp[((b * 16 + c) * H_IMG + hh) * W_IMG + ww];
                v = (x < 0.1f) ? MAX_SPIKE : x;
                kr[wv_i][i] = ((unsigned long long)__float_as_uint(v) << 8)
                              | (unsigned)i;
            }
            vals[m] = v;
        }
        v0f = vals[0]; v1f = vals[1]; v2f = vals[2];
        key0 = ((unsigned long long)__float_as_uint(v0f) << 8) | (unsigned)idx[0];
        key1 = ((unsigned long long)__float_as_uint(v1f) << 8) | (unsigned)idx[1];
        key2 = ((unsigned long long)__float_as_uint(v2f) << 8) | (unsigned)idx[2];
        if (lane == 0) sv[wv_i][F_IN] = 1.0f;    // causality sentinel
    }
    __syncthreads();

    // ---- rank sort ----
    int r0 = 0, r1 = 0, r2 = 0;
    {
        const unsigned long long* ks = kr[wv_i];
#pragma unroll 4
        for (int j = 0; j < F_IN; ++j) {
            const unsigned long long kj = ks[j];
            r0 += (kj < key0);
            r1 += (kj < key1);
            r2 += (kj < key2);
        }
    }
    __syncthreads();   // all key reads complete before we clobber kr below

    // ---- scatter sorted values + record-lo (wq row byte offset) ----
    {
        unsigned* krlo = (unsigned*)&kr[wv_i][0];   // little-endian: lo at +0
        sv[wv_i][r0] = v0f;  krlo[2 * r0] = (unsigned)lane << 8;
        sv[wv_i][r1] = v1f;  krlo[2 * r1] = (unsigned)(lane + 64) << 8;
        if (lane < F_IN - 128) {
            sv[wv_i][r2] = v2f;  krlo[2 * r2] = (unsigned)(lane + 128) << 8;
        }
    }
    __syncthreads();

    // ---- record-hi = bits of next sorted value ----
    {
        unsigned* krhi = (unsigned*)&kr[wv_i][0];
        for (int k = lane; k < F_IN; k += 64)
            krhi[2 * k + 1] = __float_as_uint(sv[wv_i][k + 1]);
    }
    __syncthreads();

    // ---- per-channel sequential scan: first valid spike == min ----
    const char* wqp = (const char*)(wq + lane);
    float s   = sv[wv_i][0];
    float ws  = 0.f;
    float iws = 0.f;
    float mn  = MAX_SPIKE;      // all-masked / never-valid lanes => exactly 100
    bool  done = false;
    for (int k = 0; k < F_IN; ++k) {
        if (s >= MAX_SPIKE) break;            // sorted: rest contribute 100
        const unsigned long long rec = kr[wv_i][k];
        const float nxt = __uint_as_float((unsigned)(rec >> 32));
        const float wvv = *(const float*)(wqp + (unsigned)rec);  // L1-hot
        ws += wvv;
        const float prod = s * wvv;           // separate rounding (no FMA)
        iws += prod;
        if (!__all(ws < 1.0f)) {              // whole-wave masked -> skip
            float d = fmaxf(ws - 1.0f, 1e-10f);  // upper clamp never binds
            const float q = iws / d;             // IEEE f32 divide
            const bool valid = (ws >= 1.0f) && (q >= s) && (q <= nxt);
            if (valid && !done) { mn = q; done = true; }
            if (__all(done)) break;           // windows increase: first = min
        }
        s = nxt;
    }
    out[(b * F_OUT + lane) * 1024 + l] = mn;
}

extern "C" void kernel_launch(void* const* d_in, const int* in_sizes, int n_in,
                              void* d_out, int out_size, void* d_ws, size_t ws_size,
                              hipStream_t stream) {
    const float* inp = (const float*)d_in[0];   // 65536 elems
    const float* w   = (const float*)d_in[1];   // 9216 elems
    float* out = (float*)d_out;                 // 262144 elems
    float* wqT = (float*)d_ws;                  // 9216 floats scratch

    quant_fused_kernel<<<36, 256, 0, stream>>>(w, wqT);
    spike_conv_kernel<<<NPIX / 4, 256, 0, stream>>>(inp, wqT, out);
}

// Round 4
// 84.540 us; speedup vs baseline: 1.4781x; 1.1838x over previous
//
#include <hip/hip_runtime.h>
#include <math.h>

// Problem constants (fixed by reference: inp (4,16,32,32) f32, weight (64,144) f32)
constexpr int F_IN   = 144;   // 16 ch * 9 taps
constexpr int F_OUT  = 64;
constexpr int H_IMG  = 32;
constexpr int W_IMG  = 32;
constexpr int NPIX   = 4 * H_IMG * W_IMG;  // 4096
constexpr int PPB    = 8;                  // pixels per block (1 wave each)
constexpr int NTHR   = PPB * 64;           // 512
#define MAX_SPIKE 100.0f

// ---------------------------------------------------------------------------
// Weight quantization (validated rounds 2-3, unchanged numerics):
// alpha = tanh(max w) == max tanh(w) exactly (correctly-rounded monotone tanh,
// w >= 0). rintf = half-to-even like np.round; mul-then-div mirrors np.
// ---------------------------------------------------------------------------
__global__ __launch_bounds__(256) void quant_fused_kernel(
    const float* __restrict__ w,
    float* __restrict__ wqT)   // (144,64) transposed
{
#pragma clang fp contract(off)
    __shared__ float wred[4];
    const int tid = threadIdx.x;

    float m = 0.f;
    for (int i = tid; i < F_OUT * F_IN; i += 256)
        m = fmaxf(m, fabsf(w[i]));
    for (int s = 32; s > 0; s >>= 1)
        m = fmaxf(m, __shfl_xor(m, s, 64));
    if ((tid & 63) == 0) wred[tid >> 6] = m;
    __syncthreads();
    const float mw = fmaxf(fmaxf(wred[0], wred[1]), fmaxf(wred[2], wred[3]));
    const float alpha = (float)::tanh((double)mw);

    const int i = blockIdx.x * 256 + tid;   // 36*256 = 9216 exactly
    const int o = i / F_IN;
    const int f = i - o * F_IN;
    const float t = (float)::tanh((double)w[i]);
    float x = t / alpha;                       // f32 divide (mirrors np)
    x = fminf(fmaxf(x, -1.f), 1.f) * 127.f;    // clip then *qmax
    const float r = rintf(x);                  // round half-to-even
    wqT[f * F_OUT + o] = r * alpha / 127.f;    // mul then div (mirrors np)
}

// ---------------------------------------------------------------------------
// Spike conv v4: 8 pixels / 512-thread block (1 wave per pixel, 1 lane per
// output channel), wq resident in LDS, scan batched by 8.
//   - u64 keys (bits<<8)|idx == exact stable argsort (values >= 0)
//   - rank sort reading key PAIRS (ds_read_b128)
//   - per-slot record: hi = bits(next sorted value), lo = f*64 (wq LDS row)
//   - scan: 18 batches of 8; per batch 4x ds_read_b128 records + 8 LDS weight
//     reads issued together (latency amortized), then cumsums; div+masks
//     skipped while __all(last ws of batch < 1) -- EXACT because wq >= 0 so
//     ws is monotone; first valid spike == min (windows increase); exits
//     checked once per batch. Per-slot math order identical to rounds 2-3
//     (validated): prod then add, IEEE f32 div, reference mask order.
// fp contract OFF so cumsums round exactly like numpy (mul, then add).
// ---------------------------------------------------------------------------
__global__ __launch_bounds__(NTHR, 4) void spike_conv_kernel(
    const float* __restrict__ inp,   // (4,16,32,32)
    const float* __restrict__ wq,    // (144,64)
    float* __restrict__ out)         // (4,64,32,32)
{
#pragma clang fp contract(off)
    __shared__ __align__(16) float wql[F_IN * F_OUT];          // 36 KB
    __shared__ __align__(16) unsigned long long kr[PPB][F_IN]; // 9 KB
    __shared__ float sv[PPB][F_IN + 1];                        // 4.5 KB

    const int tid  = threadIdx.x;
    const int lane = tid & 63;
    const int wv_i = tid >> 6;                   // wave id = pixel-in-block
    const int p    = blockIdx.x * PPB + wv_i;    // pixel id
    const int b    = p >> 10;
    const int l    = p & 1023;
    const int h    = l >> 5;
    const int w    = l & 31;

    // ---- stage wq into LDS (block-cooperative, float4) ----
    {
        const float4* src = (const float4*)wq;
        float4* dst = (float4*)wql;
        for (int i = tid; i < (F_IN * F_OUT) / 4; i += NTHR)
            dst[i] = src[i];
    }

    // ---- stage patch, build keys (feature f = c*9 + kh*3 + kw) ----
    float v0f, v1f, v2f;
    unsigned long long key0, key1, key2;
    {
        int idx[3] = { lane, lane + 64, lane + 128 };
        float vals[3];
        for (int m = 0; m < 3; ++m) {
            const int i = idx[m];
            float v = MAX_SPIKE;
            if (i < F_IN) {
                const int c  = i / 9;
                const int r  = i - c * 9;
                const int kh = r / 3;
                const int kw = r - kh * 3;
                const int hh = h + kh - 1;
                const int ww = w + kw - 1;
                float x = 0.f;
                if (hh >= 0 && hh < H_IMG && ww >= 0 && ww < W_IMG)
                    x = inp[((b * 16 + c) * H_IMG + hh) * W_IMG + ww];
                v = (x < 0.1f) ? MAX_SPIKE : x;
                kr[wv_i][i] = ((unsigned long long)__float_as_uint(v) << 8)
                              | (unsigned)i;
            }
            vals[m] = v;
        }
        v0f = vals[0]; v1f = vals[1]; v2f = vals[2];
        key0 = ((unsigned long long)__float_as_uint(v0f) << 8) | (unsigned)idx[0];
        key1 = ((unsigned long long)__float_as_uint(v1f) << 8) | (unsigned)idx[1];
        key2 = ((unsigned long long)__float_as_uint(v2f) << 8) | (unsigned)idx[2];
        if (lane == 0) sv[wv_i][F_IN] = 1.0f;    // causality sentinel
    }
    __syncthreads();

    // ---- rank sort (keys unique -> strict < == exact stable permutation) ----
    int r0 = 0, r1 = 0, r2 = 0;
    {
        const ulonglong2* ks2 = (const ulonglong2*)&kr[wv_i][0];
#pragma unroll 4
        for (int j = 0; j < F_IN / 2; ++j) {
            const ulonglong2 kk = ks2[j];
            r0 += (kk.x < key0) + (kk.y < key0);
            r1 += (kk.x < key1) + (kk.y < key1);
            r2 += (kk.x < key2) + (kk.y < key2);
        }
    }
    __syncthreads();   // all key reads complete before kr is clobbered

    // ---- scatter sorted values + record-lo (wq LDS row word offset) ----
    {
        unsigned* krlo = (unsigned*)&kr[wv_i][0];   // little-endian: lo at +0
        sv[wv_i][r0] = v0f;  krlo[2 * r0] = (unsigned)lane << 6;
        sv[wv_i][r1] = v1f;  krlo[2 * r1] = (unsigned)(lane + 64) << 6;
        if (lane < F_IN - 128) {
            sv[wv_i][r2] = v2f;  krlo[2 * r2] = (unsigned)(lane + 128) << 6;
        }
    }
    __syncthreads();

    // ---- record-hi = bits of next sorted value ----
    {
        unsigned* krhi = (unsigned*)&kr[wv_i][0];
        for (int k = lane; k < F_IN; k += 64)
            krhi[2 * k + 1] = __float_as_uint(sv[wv_i][k + 1]);
    }
    __syncthreads();

    // ---- batched scan: first valid spike == min ----
    float s   = sv[wv_i][0];
    float ws  = 0.f;
    float iws = 0.f;
    float mn  = MAX_SPIKE;      // masked / never-valid lanes => exactly 100
    bool  done = false;
    const ulonglong2* rec2 = (const ulonglong2*)&kr[wv_i][0];
    for (int k0 = 0; k0 < F_IN; k0 += 8) {
        if (s >= MAX_SPIKE) break;            // sorted: rest contribute 100
        const ulonglong2 ra = rec2[(k0 >> 1) + 0];
        const ulonglong2 rb = rec2[(k0 >> 1) + 1];
        const ulonglong2 rc = rec2[(k0 >> 1) + 2];
        const ulonglong2 rd = rec2[(k0 >> 1) + 3];
        const unsigned long long r8[8] = { ra.x, ra.y, rb.x, rb.y,
                                           rc.x, rc.y, rd.x, rd.y };
        float su[8], nx[8], wsu[8], iwsu[8];
#pragma unroll
        for (int u = 0; u < 8; ++u) {
            su[u] = s;
            nx[u] = __uint_as_float((unsigned)(r8[u] >> 32));
            const float wvv = wql[(unsigned)r8[u] + lane];  // 2-way bank: free
            ws += wvv;
            const float prod = su[u] * wvv;   // separate rounding (no FMA)
            iws += prod;
            wsu[u]  = ws;
            iwsu[u] = iws;
            s = nx[u];
        }
        // wq >= 0 => ws monotone: if last ws < 1 for all lanes, whole batch
        // is masked (contributes exactly 100) -> skip div/compare block.
        if (!__all(wsu[7] < 1.0f)) {
#pragma unroll
            for (int u = 0; u < 8; ++u) {
                const float d = fmaxf(wsu[u] - 1.0f, 1e-10f); // upper clamp never binds
                const float q = iwsu[u] / d;                  // IEEE f32 divide
                const bool valid = (wsu[u] >= 1.0f) & (q >= su[u]) & (q <= nx[u]);
                if (valid & !done) { mn = q; done = true; }
            }
            if (__all(done)) break;           // windows increase: first = min
        }
    }
    out[(b * F_OUT + lane) * 1024 + l] = mn;
}

extern "C" void kernel_launch(void* const* d_in, const int* in_sizes, int n_in,
                              void* d_out, int out_size, void* d_ws, size_t ws_size,
                              hipStream_t stream) {
    const float* inp = (const float*)d_in[0];   // 65536 elems
    const float* w   = (const float*)d_in[1];   // 9216 elems
    float* out = (float*)d_out;                 // 262144 elems
    float* wqT = (float*)d_ws;                  // 9216 floats scratch

    quant_fused_kernel<<<36, 256, 0, stream>>>(w, wqT);
    spike_conv_kernel<<<NPIX / PPB, NTHR, 0, stream>>>(inp, wqT, out);
}

// Round 5
// 80.756 us; speedup vs baseline: 1.5474x; 1.0469x over previous
//
#include <hip/hip_runtime.h>
#include <math.h>

// Problem constants (fixed by reference: inp (4,16,32,32) f32, weight (64,144) f32)
constexpr int F_IN   = 144;   // 16 ch * 9 taps
constexpr int F_OUT  = 64;
constexpr int H_IMG  = 32;
constexpr int W_IMG  = 32;
constexpr int NPIX   = 4 * H_IMG * W_IMG;  // 4096
constexpr int PPB    = 8;                  // pixels per block (1 wave each)
constexpr int NTHR   = PPB * 64;           // 512
#define MAX_SPIKE 100.0f

// ---------------------------------------------------------------------------
// Weight quantization (validated rounds 2-4, numerics unchanged):
// alpha = tanh(max|w|) == max|tanh(w)| exactly (correctly-rounded monotone
// tanh; |tanh(x)| = tanh(|x|)). rintf = half-to-even like np.round;
// mul-then-div mirrors np rounding. float4 max-reduce (9 iters vs 36).
// ---------------------------------------------------------------------------
__global__ __launch_bounds__(256) void quant_fused_kernel(
    const float* __restrict__ w,
    float* __restrict__ wqT)   // (144,64) transposed
{
#pragma clang fp contract(off)
    __shared__ float wred[4];
    const int tid = threadIdx.x;

    float m = 0.f;
    {
        const float4* w4 = (const float4*)w;
        for (int i = tid; i < (F_OUT * F_IN) / 4; i += 256) {
            const float4 v = w4[i];
            m = fmaxf(m, fmaxf(fmaxf(fabsf(v.x), fabsf(v.y)),
                               fmaxf(fabsf(v.z), fabsf(v.w))));
        }
    }
    for (int s = 32; s > 0; s >>= 1)
        m = fmaxf(m, __shfl_xor(m, s, 64));
    if ((tid & 63) == 0) wred[tid >> 6] = m;
    __syncthreads();
    const float mw = fmaxf(fmaxf(wred[0], wred[1]), fmaxf(wred[2], wred[3]));
    const float alpha = (float)::tanh((double)mw);

    const int i = blockIdx.x * 256 + tid;   // 36*256 = 9216 exactly
    const int o = i / F_IN;
    const int f = i - o * F_IN;
    const float t = (float)::tanh((double)w[i]);
    float x = t / alpha;                       // f32 divide (mirrors np)
    x = fminf(fmaxf(x, -1.f), 1.f) * 127.f;    // clip then *qmax
    const float r = rintf(x);                  // round half-to-even
    wqT[f * F_OUT + o] = r * alpha / 127.f;    // mul then div (mirrors np)
}

// ---------------------------------------------------------------------------
// Spike conv v5: 8 pixels / 512-thread block (1 wave per pixel, 1 lane per
// output channel). Changes vs v4 (math identical, bit-exact):
//   - wq staged via ASYNC __builtin_amdgcn_global_load_lds width=16
//     (wave-uniform LDS base + lane*16 == our contiguous layout); issued
//     FIRST so it overlaps patch staging + the whole rank sort.
//   - kr/sv are WAVE-PRIVATE: same-wave DS ordering is guaranteed (in-order
//     lgkmcnt), so the 3 intermediate __syncthreads are removed. ONE barrier
//     remains before the scan: makes wql visible block-wide and drains the
//     async loads (barrier implies vmcnt(0)).
//   - sort: u64 keys (bits<<8)|idx == exact stable argsort; rank via key
//     pairs (ds_read_b128, broadcast -> conflict-free).
//   - scan: batches of 8; skip div/masks while __all(batch-last ws < 1)
//     (exact: wq >= 0 -> ws monotone); first valid spike == min (windows
//     non-overlapping increasing); exits checked once per batch.
// fp contract OFF so cumsums round exactly like numpy (mul, then add).
// ---------------------------------------------------------------------------
__global__ __launch_bounds__(NTHR, 4) void spike_conv_kernel(
    const float* __restrict__ inp,   // (4,16,32,32)
    const float* __restrict__ wq,    // (144,64)
    float* __restrict__ out)         // (4,64,32,32)
{
#pragma clang fp contract(off)
    __shared__ __align__(16) float wql[F_IN * F_OUT];          // 36 KB
    __shared__ __align__(16) unsigned long long kr[PPB][F_IN]; // 9 KB
    __shared__ float sv[PPB][F_IN + 1];                        // 4.5 KB

    const int tid  = threadIdx.x;
    const int lane = tid & 63;
    const int wv_i = tid >> 6;                   // wave id = pixel-in-block
    const int p    = blockIdx.x * PPB + wv_i;    // pixel id
    const int b    = p >> 10;
    const int l    = p & 1023;
    const int h    = l >> 5;
    const int w    = l & 31;

    // ---- async stage wq -> LDS: 36 chunks of 1 KB (64 lanes x 16 B) ----
    // chunk c: lanes read wq + c*256 + lane*4, land at wql + c*256 + lane*4.
    for (int c = wv_i; c < 36; c += PPB) {
        const float* g = wq + c * 256 + lane * 4;
        __builtin_amdgcn_global_load_lds(
            (const __attribute__((address_space(1))) void*)g,
            (__attribute__((address_space(3))) void*)&wql[c * 256],
            16, 0, 0);
    }

    // ---- stage patch, build keys (feature f = c*9 + kh*3 + kw) ----
    float v0f, v1f, v2f;
    unsigned long long key0, key1, key2;
    {
        int idx[3] = { lane, lane + 64, lane + 128 };
        float vals[3];
        for (int m = 0; m < 3; ++m) {
            const int i = idx[m];
            float v = MAX_SPIKE;
            if (i < F_IN) {
                const int c  = i / 9;
                const int r  = i - c * 9;
                const int kh = r / 3;
                const int kw = r - kh * 3;
                const int hh = h + kh - 1;
                const int ww = w + kw - 1;
                float x = 0.f;
                if (hh >= 0 && hh < H_IMG && ww >= 0 && ww < W_IMG)
                    x = inp[((b * 16 + c) * H_IMG + hh) * W_IMG + ww];
                v = (x < 0.1f) ? MAX_SPIKE : x;
                kr[wv_i][i] = ((unsigned long long)__float_as_uint(v) << 8)
                              | (unsigned)i;
            }
            vals[m] = v;
        }
        v0f = vals[0]; v1f = vals[1]; v2f = vals[2];
        key0 = ((unsigned long long)__float_as_uint(v0f) << 8) | (unsigned)idx[0];
        key1 = ((unsigned long long)__float_as_uint(v1f) << 8) | (unsigned)idx[1];
        key2 = ((unsigned long long)__float_as_uint(v2f) << 8) | (unsigned)idx[2];
        if (lane == 0) sv[wv_i][F_IN] = 1.0f;    // causality sentinel
    }
    // kr/sv wave-private: same-wave DS ordering is in-order -> no barrier.

    // ---- rank sort (keys unique -> strict < == exact stable permutation) ----
    int r0 = 0, r1 = 0, r2 = 0;
    {
        const ulonglong2* ks2 = (const ulonglong2*)&kr[wv_i][0];
#pragma unroll 4
        for (int j = 0; j < F_IN / 2; ++j) {
            const ulonglong2 kk = ks2[j];   // wave-broadcast read: conflict-free
            r0 += (kk.x < key0) + (kk.y < key0);
            r1 += (kk.x < key1) + (kk.y < key1);
            r2 += (kk.x < key2) + (kk.y < key2);
        }
    }

    // ---- scatter sorted values + record-lo (wq LDS row word offset) ----
    {
        unsigned* krlo = (unsigned*)&kr[wv_i][0];   // little-endian: lo at +0
        sv[wv_i][r0] = v0f;  krlo[2 * r0] = (unsigned)lane << 6;
        sv[wv_i][r1] = v1f;  krlo[2 * r1] = (unsigned)(lane + 64) << 6;
        if (lane < F_IN - 128) {
            sv[wv_i][r2] = v2f;  krlo[2 * r2] = (unsigned)(lane + 128) << 6;
        }
    }

    // ---- record-hi = bits of next sorted value ----
    {
        unsigned* krhi = (unsigned*)&kr[wv_i][0];
        for (int k = lane; k < F_IN; k += 64)
            krhi[2 * k + 1] = __float_as_uint(sv[wv_i][k + 1]);
    }

    // ONE block barrier: wql visible to all waves + async vmcnt drained.
    __syncthreads();

    // ---- batched scan: first valid spike == min ----
    float s   = sv[wv_i][0];
    float ws  = 0.f;
    float iws = 0.f;
    float mn  = MAX_SPIKE;      // masked / never-valid lanes => exactly 100
    bool  done = false;
    const ulonglong2* rec2 = (const ulonglong2*)&kr[wv_i][0];
    for (int k0 = 0; k0 < F_IN; k0 += 8) {
        if (s >= MAX_SPIKE) break;            // sorted: rest contribute 100
        const ulonglong2 ra = rec2[(k0 >> 1) + 0];
        const ulonglong2 rb = rec2[(k0 >> 1) + 1];
        const ulonglong2 rc = rec2[(k0 >> 1) + 2];
        const ulonglong2 rd = rec2[(k0 >> 1) + 3];
        const unsigned long long r8[8] = { ra.x, ra.y, rb.x, rb.y,
                                           rc.x, rc.y, rd.x, rd.y };
        float su[8], nx[8], wsu[8], iwsu[8];
#pragma unroll
        for (int u = 0; u < 8; ++u) {
            su[u] = s;
            nx[u] = __uint_as_float((unsigned)(r8[u] >> 32));
            const float wvv = wql[(unsigned)r8[u] + lane];  // 2-way bank: free
            ws += wvv;
            const float prod = su[u] * wvv;   // separate rounding (no FMA)
            iws += prod;
            wsu[u]  = ws;
            iwsu[u] = iws;
            s = nx[u];
        }
        // wq >= 0 => ws monotone: if last ws of batch < 1 for all lanes, the
        // whole batch is masked (contributes exactly 100) -> skip div/compares.
        if (!__all(wsu[7] < 1.0f)) {
#pragma unroll
            for (int u = 0; u < 8; ++u) {
                const float d = fmaxf(wsu[u] - 1.0f, 1e-10f); // upper clamp never binds
                const float q = iwsu[u] / d;                  // IEEE f32 divide
                const bool valid = (wsu[u] >= 1.0f) & (q >= su[u]) & (q <= nx[u]);
                if (valid & !done) { mn = q; done = true; }
            }
            if (__all(done)) break;           // windows increase: first = min
        }
    }
    out[(b * F_OUT + lane) * 1024 + l] = mn;
}

extern "C" void kernel_launch(void* const* d_in, const int* in_sizes, int n_in,
                              void* d_out, int out_size, void* d_ws, size_t ws_size,
                              hipStream_t stream) {
    const float* inp = (const float*)d_in[0];   // 65536 elems
    const float* w   = (const float*)d_in[1];   // 9216 elems
    float* out = (float*)d_out;                 // 262144 elems
    float* wqT = (float*)d_ws;                  // 9216 floats scratch

    quant_fused_kernel<<<36, 256, 0, stream>>>(w, wqT);
    spike_conv_kernel<<<NPIX / PPB, NTHR, 0, stream>>>(inp, wqT, out);
}

// Round 6
// 80.731 us; speedup vs baseline: 1.5479x; 1.0003x over previous
//
#include <hip/hip_runtime.h>
#include <math.h>

// Problem constants (fixed by reference: inp (4,16,32,32) f32, weight (64,144) f32)
constexpr int F_IN   = 144;   // 16 ch * 9 taps
constexpr int F_OUT  = 64;
constexpr int H_IMG  = 32;
constexpr int W_IMG  = 32;
constexpr int NPIX   = 4 * H_IMG * W_IMG;  // 4096
constexpr int PPB    = 8;                  // pixels per block (1 wave each)
constexpr int NTHR   = PPB * 64;           // 512
#define MAX_SPIKE 100.0f

// ---------------------------------------------------------------------------
// Weight quantization. ROUND-6 CHANGE: tanhf instead of (float)tanh(double).
// Cross-round timing fit showed each dependent f64 ocml tanh call costs
// ~25 us (quant kernel ~52 us total = the hidden elephant; spike is ~26 us).
// tanhf is <=1 ulp (same ulp-distance class from the numpy f32 reference as
// the correctly-rounded f64 version that passed at the 0.0039 floor), and
// rint-quantization snaps to integers, wiping sub-boundary differences.
// alpha = tanhf(max|w|) == max tanhf(|w|) (monotone impl, w >= 0).
// rintf = half-to-even like np.round; mul-then-div mirrors np rounding.
// ---------------------------------------------------------------------------
__global__ __launch_bounds__(256) void quant_fused_kernel(
    const float* __restrict__ w,
    float* __restrict__ wqT)   // (144,64) transposed
{
#pragma clang fp contract(off)
    __shared__ float wred[4];
    const int tid = threadIdx.x;

    float m = 0.f;
    {
        const float4* w4 = (const float4*)w;
        for (int i = tid; i < (F_OUT * F_IN) / 4; i += 256) {
            const float4 v = w4[i];
            m = fmaxf(m, fmaxf(fmaxf(fabsf(v.x), fabsf(v.y)),
                               fmaxf(fabsf(v.z), fabsf(v.w))));
        }
    }
    for (int s = 32; s > 0; s >>= 1)
        m = fmaxf(m, __shfl_xor(m, s, 64));
    if ((tid & 63) == 0) wred[tid >> 6] = m;
    __syncthreads();
    const float mw = fmaxf(fmaxf(wred[0], wred[1]), fmaxf(wred[2], wred[3]));
    const float alpha = tanhf(mw);

    const int i = blockIdx.x * 256 + tid;   // 36*256 = 9216 exactly
    const int o = i / F_IN;
    const int f = i - o * F_IN;
    const float t = tanhf(w[i]);
    float x = t / alpha;                       // f32 divide (mirrors np)
    x = fminf(fmaxf(x, -1.f), 1.f) * 127.f;    // clip then *qmax
    const float r = rintf(x);                  // round half-to-even
    wqT[f * F_OUT + o] = r * alpha / 127.f;    // mul then div (mirrors np)
}

// ---------------------------------------------------------------------------
// Spike conv v5 (unchanged from round 5 -- isolate the quant variable):
// 8 pixels / 512-thread block, wq in LDS via async global_load_lds width=16,
// one block barrier, u64-key stable rank sort, batched-by-8 scan with
// first-valid==min early exit. Bit-exact vs validated rounds 2-5.
// ---------------------------------------------------------------------------
__global__ __launch_bounds__(NTHR, 4) void spike_conv_kernel(
    const float* __restrict__ inp,   // (4,16,32,32)
    const float* __restrict__ wq,    // (144,64)
    float* __restrict__ out)         // (4,64,32,32)
{
#pragma clang fp contract(off)
    __shared__ __align__(16) float wql[F_IN * F_OUT];          // 36 KB
    __shared__ __align__(16) unsigned long long kr[PPB][F_IN]; // 9 KB
    __shared__ float sv[PPB][F_IN + 1];                        // 4.5 KB

    const int tid  = threadIdx.x;
    const int lane = tid & 63;
    const int wv_i = tid >> 6;                   // wave id = pixel-in-block
    const int p    = blockIdx.x * PPB + wv_i;    // pixel id
    const int b    = p >> 10;
    const int l    = p & 1023;
    const int h    = l >> 5;
    const int w    = l & 31;

    // ---- async stage wq -> LDS: 36 chunks of 1 KB (64 lanes x 16 B) ----
    for (int c = wv_i; c < 36; c += PPB) {
        const float* g = wq + c * 256 + lane * 4;
        __builtin_amdgcn_global_load_lds(
            (const __attribute__((address_space(1))) void*)g,
            (__attribute__((address_space(3))) void*)&wql[c * 256],
            16, 0, 0);
    }

    // ---- stage patch, build keys (feature f = c*9 + kh*3 + kw) ----
    float v0f, v1f, v2f;
    unsigned long long key0, key1, key2;
    {
        int idx[3] = { lane, lane + 64, lane + 128 };
        float vals[3];
        for (int m = 0; m < 3; ++m) {
            const int i = idx[m];
            float v = MAX_SPIKE;
            if (i < F_IN) {
                const int c  = i / 9;
                const int r  = i - c * 9;
                const int kh = r / 3;
                const int kw = r - kh * 3;
                const int hh = h + kh - 1;
                const int ww = w + kw - 1;
                float x = 0.f;
                if (hh >= 0 && hh < H_IMG && ww >= 0 && ww < W_IMG)
                    x = inp[((b * 16 + c) * H_IMG + hh) * W_IMG + ww];
                v = (x < 0.1f) ? MAX_SPIKE : x;
                kr[wv_i][i] = ((unsigned long long)__float_as_uint(v) << 8)
                              | (unsigned)i;
            }
            vals[m] = v;
        }
        v0f = vals[0]; v1f = vals[1]; v2f = vals[2];
        key0 = ((unsigned long long)__float_as_uint(v0f) << 8) | (unsigned)idx[0];
        key1 = ((unsigned long long)__float_as_uint(v1f) << 8) | (unsigned)idx[1];
        key2 = ((unsigned long long)__float_as_uint(v2f) << 8) | (unsigned)idx[2];
        if (lane == 0) sv[wv_i][F_IN] = 1.0f;    // causality sentinel
    }
    // kr/sv wave-private: same-wave DS ordering is in-order -> no barrier.

    // ---- rank sort (keys unique -> strict < == exact stable permutation) ----
    int r0 = 0, r1 = 0, r2 = 0;
    {
        const ulonglong2* ks2 = (const ulonglong2*)&kr[wv_i][0];
#pragma unroll 4
        for (int j = 0; j < F_IN / 2; ++j) {
            const ulonglong2 kk = ks2[j];   // wave-broadcast read: conflict-free
            r0 += (kk.x < key0) + (kk.y < key0);
            r1 += (kk.x < key1) + (kk.y < key1);
            r2 += (kk.x < key2) + (kk.y < key2);
        }
    }

    // ---- scatter sorted values + record-lo (wq LDS row word offset) ----
    {
        unsigned* krlo = (unsigned*)&kr[wv_i][0];   // little-endian: lo at +0
        sv[wv_i][r0] = v0f;  krlo[2 * r0] = (unsigned)lane << 6;
        sv[wv_i][r1] = v1f;  krlo[2 * r1] = (unsigned)(lane + 64) << 6;
        if (lane < F_IN - 128) {
            sv[wv_i][r2] = v2f;  krlo[2 * r2] = (unsigned)(lane + 128) << 6;
        }
    }

    // ---- record-hi = bits of next sorted value ----
    {
        unsigned* krhi = (unsigned*)&kr[wv_i][0];
        for (int k = lane; k < F_IN; k += 64)
            krhi[2 * k + 1] = __float_as_uint(sv[wv_i][k + 1]);
    }

    // ONE block barrier: wql visible to all waves + async vmcnt drained.
    __syncthreads();

    // ---- batched scan: first valid spike == min ----
    float s   = sv[wv_i][0];
    float ws  = 0.f;
    float iws = 0.f;
    float mn  = MAX_SPIKE;      // masked / never-valid lanes => exactly 100
    bool  done = false;
    const ulonglong2* rec2 = (const ulonglong2*)&kr[wv_i][0];
    for (int k0 = 0; k0 < F_IN; k0 += 8) {
        if (s >= MAX_SPIKE) break;            // sorted: rest contribute 100
        const ulonglong2 ra = rec2[(k0 >> 1) + 0];
        const ulonglong2 rb = rec2[(k0 >> 1) + 1];
        const ulonglong2 rc = rec2[(k0 >> 1) + 2];
        const ulonglong2 rd = rec2[(k0 >> 1) + 3];
        const unsigned long long r8[8] = { ra.x, ra.y, rb.x, rb.y,
                                           rc.x, rc.y, rd.x, rd.y };
        float su[8], nx[8], wsu[8], iwsu[8];
#pragma unroll
        for (int u = 0; u < 8; ++u) {
            su[u] = s;
            nx[u] = __uint_as_float((unsigned)(r8[u] >> 32));
            const float wvv = wql[(unsigned)r8[u] + lane];  // 2-way bank: free
            ws += wvv;
            const float prod = su[u] * wvv;   // separate rounding (no FMA)
            iws += prod;
            wsu[u]  = ws;
            iwsu[u] = iws;
            s = nx[u];
        }
        // wq >= 0 => ws monotone: if last ws of batch < 1 for all lanes, the
        // whole batch is masked (contributes exactly 100) -> skip div/compares.
        if (!__all(wsu[7] < 1.0f)) {
#pragma unroll
            for (int u = 0; u < 8; ++u) {
                const float d = fmaxf(wsu[u] - 1.0f, 1e-10f); // upper clamp never binds
                const float q = iwsu[u] / d;                  // IEEE f32 divide
                const bool valid = (wsu[u] >= 1.0f) & (q >= su[u]) & (q <= nx[u]);
                if (valid & !done) { mn = q; done = true; }
            }
            if (__all(done)) break;           // windows increase: first = min
        }
    }
    out[(b * F_OUT + lane) * 1024 + l] = mn;
}

extern "C" void kernel_launch(void* const* d_in, const int* in_sizes, int n_in,
                              void* d_out, int out_size, void* d_ws, size_t ws_size,
                              hipStream_t stream) {
    const float* inp = (const float*)d_in[0];   // 65536 elems
    const float* w   = (const float*)d_in[1];   // 9216 elems
    float* out = (float*)d_out;                 // 262144 elems
    float* wqT = (float*)d_ws;                  // 9216 floats scratch

    quant_fused_kernel<<<36, 256, 0, stream>>>(w, wqT);
    spike_conv_kernel<<<NPIX / PPB, NTHR, 0, stream>>>(inp, wqT, out);
}